// Round 1
// 187.213 us; speedup vs baseline: 1.1390x; 1.1390x over previous
//
#include <hip/hip_runtime.h>
#include <stdint.h>

#define AS1 __attribute__((address_space(1)))
#define AS3 __attribute__((address_space(3)))

typedef __attribute__((ext_vector_type(8))) short short8;
typedef __attribute__((ext_vector_type(4))) float floatx4;

__device__ __forceinline__ unsigned short f2b_rne(float f) {
  union { float f; unsigned u; } c; c.f = f;
  unsigned u = c.u;
  unsigned r = u + 0x7fffu + ((u >> 16) & 1u);
  return (unsigned short)(r >> 16);
}

// ---------------------------------------------------------------------------
// Weight prep: Wt[n][k'] = bf16(W_seg[k][c])  (B^T layout, K contiguous),
// with a 16B-chunk XOR swizzle baked in so LDS ds_read_b128 is conflict-free:
//   chunk c (k>>3, 0..31) of row n stored at:
//     n < 768  : c' = (c&~7) | ((c^n)&7)   (3-bit XOR, stays in 128B window)
//     n >= 768 : c' = (c&~3) | ((c^n)&3)   (2-bit XOR, stays in 64B window)
// rows 0..255=W_val, 256..511=W_so, 512..767=W_tso, 768..895=W_aw, 896..1023=W_taw
// ---------------------------------------------------------------------------
__global__ void prep_weights(const float* __restrict__ Wv,  const float* __restrict__ bv,
                             const float* __restrict__ Wso, const float* __restrict__ bso,
                             const float* __restrict__ Waw, const float* __restrict__ baw,
                             const float* __restrict__ Wtso,const float* __restrict__ btso,
                             const float* __restrict__ Wtaw,const float* __restrict__ btaw,
                             unsigned short* __restrict__ Wt, float* __restrict__ bcat) {
  int n = blockIdx.x;   // 0..1023
  int k = threadIdx.x;  // 0..255
  const float* W; const float* b; int c, N;
  if (n < 256)      { W = Wv;   b = bv;   c = n;       N = 256; }
  else if (n < 512) { W = Wso;  b = bso;  c = n - 256; N = 256; }
  else if (n < 768) { W = Wtso; b = btso; c = n - 512; N = 256; }
  else if (n < 896) { W = Waw;  b = baw;  c = n - 768; N = 128; }
  else              { W = Wtaw; b = btaw; c = n - 896; N = 128; }
  int c8 = k >> 3, lo = k & 7;
  int cs;
  if (n < 768) cs = (c8 & ~7) | ((c8 ^ n) & 7);
  else         cs = (c8 & ~3) | ((c8 ^ n) & 3);
  Wt[n * 256 + cs * 8 + lo] = f2b_rne(W[(size_t)k * N + c]);
  if (k == 0) bcat[n] = b[c];
}

// ---------------------------------------------------------------------------
// Fused kernel: one block per 64 query rows. Per block:
//   phase 0: stage X-tile (64x256 bf16, swizzled) -> nt 0,1 (value)
//   phase 1: stage Q-tile                          -> nt 2..5 (so, tso)
//   aw phase: per-wave head-pair GEMM (swapped operands) + register softmax.
// MFMA operands are SWAPPED (weights as first operand) so each lane's floatx4
// spans 4 consecutive output columns -> float4 stores + in-register softmax.
// ---------------------------------------------------------------------------
__global__ __launch_bounds__(256, 3)
void fused_all(const float* __restrict__ Q, const float* __restrict__ X,
               const unsigned short* __restrict__ Wt, const float* __restrict__ bcat,
               float* __restrict__ out, int M) {
  __shared__ __align__(16) char lds[49152];   // [0,32768) A 64x256 bf16 swz; [32768,49152) B

  const int tid  = threadIdx.x;
  const int lane = tid & 63;
  const int wid  = tid >> 6;
  const int lrow = lane & 15;
  const int quad = lane >> 4;
  const int mw   = (wid >> 1) * 32;   // wave's 32-row span (main)
  const int nw   = (wid & 1) * 64;    // wave's 64-col span (main)
  const int mBase = blockIdx.x * 64;

  for (int phase = 0; phase < 2; ++phase) {
    const float* A = (phase == 0) ? X : Q;
    // ---- stage A: 64x256 fp32 -> bf16, swizzled, via regs ----
    {
      float4 va[16];
#pragma unroll
      for (int i = 0; i < 16; ++i) {
        int id = i * 256 + tid;
        int r = id >> 6, c4 = id & 63;
        va[i] = *(const float4*)(A + (size_t)(mBase + r) * 256 + c4 * 4);
      }
#pragma unroll
      for (int i = 0; i < 16; ++i) {
        int id = i * 256 + tid;
        int r = id >> 6, c4 = id & 63;
        int c8 = c4 >> 1, hf = c4 & 1;
        int pos = (c8 & ~7) | ((c8 ^ r) & 7);
        uint2 pk;
        pk.x = ((unsigned)f2b_rne(va[i].y) << 16) | f2b_rne(va[i].x);
        pk.y = ((unsigned)f2b_rne(va[i].w) << 16) | f2b_rne(va[i].z);
        *(uint2*)(lds + r * 512 + pos * 16 + hf * 8) = pk;
      }
    }
    const int ntBeg = phase ? 2 : 0;
    const int ntEnd = phase ? 6 : 2;
    for (int nt = ntBeg; nt < ntEnd; ++nt) {
      const int nBase = nt * 128;
      const unsigned short* Bb = Wt + (size_t)nBase * 256;
      floatx4 acc[2][4] = {};
      for (int s = 0; s < 4; ++s) {          // K_STEP = 64
        // ---- B stage: 128 rows x 128B window = 16 KB, 4 x 16B per thread ----
#pragma unroll
        for (int ci = 0; ci < 4; ++ci) {
          int g = ci * 256 + tid;
          int r = g >> 3, j = g & 7;
          const unsigned short* src = Bb + (size_t)r * 256 + s * 64 + j * 8;
          unsigned ldsoff = 32768u + (unsigned)((ci * 256 + (tid & ~63)) * 16);
          __builtin_amdgcn_global_load_lds((const AS1 void*)src,
                                           (AS3 void*)(lds + ldsoff), 16, 0, 0);
        }
        __syncthreads();
        short8 af[2][2], bf[4][2];
#pragma unroll
        for (int mi = 0; mi < 2; ++mi) {
          int row = mw + mi * 16 + lrow;
#pragma unroll
          for (int kk = 0; kk < 2; ++kk) {
            int j = kk * 4 + quad;
            af[mi][kk] = *(const short8*)(lds + row * 512 + (s * 8 + (j ^ (row & 7))) * 16);
          }
        }
#pragma unroll
        for (int ni = 0; ni < 4; ++ni) {
          int r = nw + ni * 16 + lrow;
#pragma unroll
          for (int kk = 0; kk < 2; ++kk) {
            int j = kk * 4 + quad;
            bf[ni][kk] = *(const short8*)(lds + 32768 + r * 128 + ((j ^ (r & 7)) * 16));
          }
        }
#pragma unroll
        for (int kk = 0; kk < 2; ++kk)
#pragma unroll
          for (int mi = 0; mi < 2; ++mi)
#pragma unroll
            for (int ni = 0; ni < 4; ++ni)
              acc[mi][ni] = __builtin_amdgcn_mfma_f32_16x16x32_bf16(
                  bf[ni][kk], af[mi][kk], acc[mi][ni], 0, 0, 0);  // swapped: D[ncol][qrow]
        __syncthreads();
      }
      // ---- epilogue: lane holds 4 consecutive cols -> float4 stores ----
      const int seg = nt >> 1, halfn = nt & 1;
      float* O = out + (size_t)seg * ((size_t)M * 256) + halfn * 128;
#pragma unroll
      for (int ni = 0; ni < 4; ++ni) {
        float4 b4 = *(const float4*)(bcat + nBase + nw + ni * 16 + quad * 4);
#pragma unroll
        for (int mi = 0; mi < 2; ++mi) {
          int row = mBase + mw + mi * 16 + lrow;
          float4 v;
          v.x = acc[mi][ni][0] + b4.x;
          v.y = acc[mi][ni][1] + b4.y;
          v.z = acc[mi][ni][2] + b4.z;
          v.w = acc[mi][ni][3] + b4.w;
          *(float4*)(O + (size_t)row * 256 + nw + ni * 16 + quad * 4) = v;
        }
      }
    }
  }

  // ------------------------- aw phase -------------------------
  // Wave wid owns heads {2*wid, 2*wid+1}. Per-wave slice: 64 Wt rows
  // (caw h0,h1 then taw h0,h1) x 32-k window = 4 KB at Bs + wid*4096.
  // acc2[qt][t]: qt = qrow-tile (16 rows), t = {caw h0, caw h1, taw h0, taw h1}.
  floatx4 acc2[4][4] = {};
  for (int s = 0; s < 8; ++s) {              // K_STEP = 32
#pragma unroll
    for (int ci = 0; ci < 4; ++ci) {
      int g = ci * 64 + lane;
      int sr = g >> 2, j = g & 3;
      int n = (sr < 32) ? (768 + 32 * wid + sr) : (896 + 32 * wid + (sr - 32));
      const unsigned short* src = Wt + (size_t)n * 256 + s * 32 + j * 8;
      unsigned ldsoff = 32768u + (unsigned)(wid * 4096 + ci * 1024);
      __builtin_amdgcn_global_load_lds((const AS1 void*)src,
                                       (AS3 void*)(lds + ldsoff), 16, 0, 0);
    }
    __syncthreads();
    short8 wa[4], qf[4];
#pragma unroll
    for (int t = 0; t < 4; ++t) {
      wa[t] = *(const short8*)(lds + 32768 + wid * 4096 + (t * 16 + lrow) * 64 +
                               (quad ^ (lrow & 3)) * 16);
    }
#pragma unroll
    for (int qt = 0; qt < 4; ++qt) {
      int row = qt * 16 + lrow;
      int cg = s * 4 + quad;
      int pos = (cg & ~7) | ((cg ^ (row & 7)) & 7);
      qf[qt] = *(const short8*)(lds + row * 512 + pos * 16);
    }
#pragma unroll
    for (int qt = 0; qt < 4; ++qt)
#pragma unroll
      for (int t = 0; t < 4; ++t)
        acc2[qt][t] = __builtin_amdgcn_mfma_f32_16x16x32_bf16(
            wa[t], qf[qt], acc2[qt][t], 0, 0, 0);   // D[wcol][qrow]
    __syncthreads();
  }

  // ---- softmax over 32 (16 caw + 16 taw) per (row, head), in registers ----
  float* awc = out + (size_t)3 * ((size_t)M * 256);
  float* awt = awc + (size_t)M * 128;
#pragma unroll
  for (int hp = 0; hp < 2; ++hp) {
    const int h = 2 * wid + hp;
    float4 bc = *(const float4*)(bcat + 768 + h * 16 + quad * 4);
    float4 bt = *(const float4*)(bcat + 896 + h * 16 + quad * 4);
#pragma unroll
    for (int qt = 0; qt < 4; ++qt) {
      float c0 = acc2[qt][hp][0] + bc.x;
      float c1 = acc2[qt][hp][1] + bc.y;
      float c2 = acc2[qt][hp][2] + bc.z;
      float c3 = acc2[qt][hp][3] + bc.w;
      float t0 = acc2[qt][2 + hp][0] + bt.x;
      float t1 = acc2[qt][2 + hp][1] + bt.y;
      float t2 = acc2[qt][2 + hp][2] + bt.z;
      float t3 = acc2[qt][2 + hp][3] + bt.w;
      float mx = fmaxf(fmaxf(fmaxf(c0, c1), fmaxf(c2, c3)),
                       fmaxf(fmaxf(t0, t1), fmaxf(t2, t3)));
      mx = fmaxf(mx, __shfl_xor(mx, 16));
      mx = fmaxf(mx, __shfl_xor(mx, 32));
      float e0 = __expf(c0 - mx), e1 = __expf(c1 - mx);
      float e2 = __expf(c2 - mx), e3 = __expf(c3 - mx);
      float f0 = __expf(t0 - mx), f1 = __expf(t1 - mx);
      float f2 = __expf(t2 - mx), f3 = __expf(t3 - mx);
      float sm = ((e0 + e1) + (e2 + e3)) + ((f0 + f1) + (f2 + f3));
      sm += __shfl_xor(sm, 16);
      sm += __shfl_xor(sm, 32);
      float inv = 1.0f / sm;
      int row = mBase + qt * 16 + lrow;
      float4 oc = make_float4(e0 * inv, e1 * inv, e2 * inv, e3 * inv);
      float4 ot = make_float4(f0 * inv, f1 * inv, f2 * inv, f3 * inv);
      *(float4*)(awc + (size_t)row * 128 + h * 16 + quad * 4) = oc;
      *(float4*)(awt + (size_t)row * 128 + h * 16 + quad * 4) = ot;
    }
  }
}

// ---------------------------------------------------------------------------
extern "C" void kernel_launch(void* const* d_in, const int* in_sizes, int n_in,
                              void* d_out, int out_size, void* d_ws, size_t ws_size,
                              hipStream_t stream) {
  const float* Q    = (const float*)d_in[0];
  const float* Xf   = (const float*)d_in[1];
  const float* Wv   = (const float*)d_in[2];
  const float* bv   = (const float*)d_in[3];
  const float* Wso  = (const float*)d_in[4];
  const float* bso  = (const float*)d_in[5];
  const float* Waw  = (const float*)d_in[6];
  const float* baw  = (const float*)d_in[7];
  const float* Wtso = (const float*)d_in[8];
  const float* btso = (const float*)d_in[9];
  const float* Wtaw = (const float*)d_in[10];
  const float* btaw = (const float*)d_in[11];
  float* out = (float*)d_out;

  unsigned short* Wt = (unsigned short*)d_ws;               // 512 KB
  float* bcat = (float*)((char*)d_ws + 1024 * 256 * 2);     // 4 KB

  int M = in_sizes[0] / 256;  // 97920

  prep_weights<<<1024, 256, 0, stream>>>(Wv, bv, Wso, bso, Waw, baw,
                                         Wtso, btso, Wtaw, btaw, Wt, bcat);

  fused_all<<<M / 64, 256, 0, stream>>>(Q, Xf, Wt, bcat, out, M);
}